// Round 3
// baseline (1108.183 us; speedup 1.0000x reference)
//
#include <hip/hip_runtime.h>

// ---------------------------------------------------------------------------
// TensorProductWithSphericalHarmonicsLinear: out = R(v) * ((R(v)^T * x) @ W)
// R block-diagonal per irrep (32x0e+32x1o+32x2e+32x3o), Wigner D(alpha,beta,0).
// D = exp(alpha*X1) * exp(beta*X0);  exp(alpha*X1) closed form (pair rotations),
// exp(beta*X0) via spectral projectors of S=-X0^2 (compile-time constants).
// ---------------------------------------------------------------------------

typedef unsigned short ushort_t;
typedef unsigned int uint32;
typedef __attribute__((ext_vector_type(8))) short bf16x8;
typedef __attribute__((ext_vector_type(4))) float f32x4;

// ------------------------- compile-time fixed matrices ----------------------
struct FixTable { float v[495]; };  // l=1 @0 (27), l=2 @27 (125), l=3 @152 (343)

constexpr double csqrt(double x) {
  double g = x > 1.0 ? x : 1.0;
  for (int i = 0; i < 48; ++i) g = 0.5 * (g + x / g);
  return g;
}

constexpr FixTable make_fix() {
  FixTable F{};
  const double is2 = 1.0 / csqrt(2.0);
  for (int l = 1; l <= 3; ++l) {
    const int d = 2 * l + 1;
    const int base = (l == 1) ? 0 : (l == 2 ? 27 : 152);
    // Q (complex change of basis, reference convention; global phase dropped)
    double Qre[7][7] = {}, Qim[7][7] = {};
    for (int m = -l; m < 0; ++m) {
      Qre[l + m][l - m] = is2;      // q[l+m, l+|m|]
      Qim[l + m][l + m] = -is2;     // q[l+m, l-|m|] = -i/sqrt2
    }
    Qre[l][l] = 1.0;
    for (int m = 1; m <= l; ++m) {
      const double s = (m & 1) ? -1.0 : 1.0;
      Qre[l + m][l + m] = s * is2;
      Qim[l + m][l - m] = s * is2;
    }
    // X0 in complex basis: tridiagonal real antisymmetric
    double X0c[7][7] = {};
    for (int r = 0; r + 1 < d; ++r) {
      const double mm = (double)(r - l);
      const double am = 0.5 * csqrt((double)(l * (l + 1)) - mm * (mm + 1.0));
      X0c[r][r + 1] = am;
      X0c[r + 1][r] = -am;
    }
    // T = X0c * Q  (X0c real)
    double Tre[7][7] = {}, Tim[7][7] = {};
    for (int i = 0; i < d; ++i)
      for (int j = 0; j < d; ++j) {
        double sre = 0.0, sim = 0.0;
        for (int r = 0; r < d; ++r) { sre += X0c[i][r] * Qre[r][j]; sim += X0c[i][r] * Qim[r][j]; }
        Tre[i][j] = sre; Tim[i][j] = sim;
      }
    // X0r = Re(Q^H T)
    double X0r[7][7] = {};
    for (int p = 0; p < d; ++p)
      for (int q = 0; q < d; ++q) {
        double s = 0.0;
        for (int r = 0; r < d; ++r) s += Qre[r][p] * Tre[r][q] + Qim[r][p] * Tim[r][q];
        X0r[p][q] = s;
      }
    // S = -X0r^2  (eigenvalues m^2)
    double S[7][7] = {};
    for (int i = 0; i < d; ++i)
      for (int j = 0; j < d; ++j) {
        double s = 0.0;
        for (int r = 0; r < d; ++r) s += X0r[i][r] * X0r[r][j];
        S[i][j] = -s;
      }
    // projectors Q_m and X0*Q_m/m
    for (int m = 0; m <= l; ++m) {
      double P[7][7] = {};
      for (int i = 0; i < d; ++i) P[i][i] = 1.0;
      for (int k = 0; k <= l; ++k) {
        if (k == m) continue;
        double Pn[7][7] = {};
        const double den = (double)(m * m - k * k);
        for (int i = 0; i < d; ++i)
          for (int j = 0; j < d; ++j) {
            double s = 0.0;
            for (int r = 0; r < d; ++r) s += P[i][r] * S[r][j];
            Pn[i][j] = (s - (double)(k * k) * P[i][j]) / den;
          }
        for (int i = 0; i < d; ++i)
          for (int j = 0; j < d; ++j) P[i][j] = Pn[i][j];
      }
      for (int i = 0; i < d; ++i)
        for (int j = 0; j < d; ++j)
          F.v[base + m * d * d + i * d + j] = (float)P[i][j];
      if (m >= 1) {
        for (int i = 0; i < d; ++i)
          for (int j = 0; j < d; ++j) {
            double s = 0.0;
            for (int r = 0; r < d; ++r) s += X0r[i][r] * P[r][j];
            F.v[base + (l + 1) * d * d + (m - 1) * d * d + i * d + j] = (float)(s / (double)m);
          }
      }
    }
  }
  return F;
}

__constant__ FixTable c_fix = make_fix();

// ------------------------------- helpers -----------------------------------
__device__ __forceinline__ ushort_t f2bf(float f) {
  uint32 u = __builtin_bit_cast(uint32, f);
  uint32 r = (u + 0x7FFFu + ((u >> 16) & 1u)) >> 16;
  return (ushort_t)r;
}
__device__ __forceinline__ float bf2f(ushort_t b) {
  uint32 u = ((uint32)b) << 16;
  return __builtin_bit_cast(float, u);
}
__device__ __forceinline__ void gload_lds16(const void* g, void* l) {
  __builtin_amdgcn_global_load_lds((const __attribute__((address_space(1))) void*)g,
                                   (__attribute__((address_space(3))) void*)l, 16, 0, 0);
}

// --------------------------- W -> W^T (bf16) --------------------------------
__global__ void convert_Wt(const float* __restrict__ W, ushort_t* __restrict__ Wt) {
  int idx = blockIdx.x * 256 + threadIdx.x;  // 512*512 total
  int k = idx & 511, c = idx >> 9;
  Wt[c * 512 + k] = f2bf(W[k * 512 + c]);
}

// --------------------------- per-row Wigner D -------------------------------
template <int L>
__device__ __forceinline__ void makeD(const float* __restrict__ fixl,
                                      const float* ca, const float* sa,
                                      const float* cb, const float* sb,
                                      float* __restrict__ out) {
  constexpr int d = 2 * L + 1;
  float E[d * d];
#pragma unroll
  for (int i = 0; i < d * d; ++i) E[i] = fixl[i];
#pragma unroll
  for (int m = 1; m <= L; ++m) {
    const float* Cm = fixl + m * d * d;
    const float* Sm = fixl + (L + 1) * d * d + (m - 1) * d * d;
#pragma unroll
    for (int i = 0; i < d * d; ++i) E[i] += cb[m] * Cm[i] + sb[m] * Sm[i];
  }
  // left-multiply by exp(alpha*X1): rows (L-m, L+m) mix with cos/sin(m*alpha)
#pragma unroll
  for (int m = 1; m <= L; ++m) {
#pragma unroll
    for (int j = 0; j < d; ++j) {
      float lo = E[(L - m) * d + j], hi = E[(L + m) * d + j];
      E[(L - m) * d + j] = ca[m] * lo + sa[m] * hi;
      E[(L + m) * d + j] = -sa[m] * lo + ca[m] * hi;
    }
  }
#pragma unroll
  for (int i = 0; i < d * d; ++i) out[i] = E[i];
}

__global__ void compute_D(const float* __restrict__ vec, float* __restrict__ Dout, int N) {
  int n = blockIdx.x * blockDim.x + threadIdx.x;
  if (n >= N) return;
  float vx = vec[3 * n + 0], vy = vec[3 * n + 1], vz = vec[3 * n + 2];
  float r = sqrtf(vx * vx + vy * vy + vz * vz);
  float xx = fminf(fmaxf(vx / r, -1.f), 1.f);
  float yy = fminf(fmaxf(vy / r, -1.f), 1.f);
  float zz = fminf(fmaxf(vz / r, -1.f), 1.f);
  float beta = acosf(yy);
  float alpha = atan2f(xx, zz);
  float ca[4], sa[4], cb[4], sb[4];
#pragma unroll
  for (int m = 1; m <= 3; ++m) {
    ca[m] = cosf((float)m * alpha); sa[m] = sinf((float)m * alpha);
    cb[m] = cosf((float)m * beta);  sb[m] = sinf((float)m * beta);
  }
  float* Dn = Dout + (size_t)n * 84;
  Dn[0] = 1.f;
  makeD<1>(c_fix.v + 0,   ca, sa, cb, sb, Dn + 1);
  makeD<2>(c_fix.v + 27,  ca, sa, cb, sb, Dn + 10);
  makeD<3>(c_fix.v + 152, ca, sa, cb, sb, Dn + 35);
}

// ----------------------- inverse rotate -> bf16 x ---------------------------
__global__ void rotate_inv(const float* __restrict__ in, const float* __restrict__ Dm,
                           ushort_t* __restrict__ xo, long long total) {
  long long idx = (long long)blockIdx.x * blockDim.x + threadIdx.x;
  if (idx >= total) return;
  const int k = (int)(idx & 511);
  const long long n = idx >> 9;
  const float* Dn = Dm + n * 84;
  const float* xr = in + (n << 9);
  float acc;
  if (k < 32) {
    acc = xr[k];
  } else if (k < 128) {
    const int t = k - 32; const int i = t % 3; const int gb = 32 + t - i;
    const float* D1 = Dn + 1;
    acc = D1[i] * xr[gb] + D1[3 + i] * xr[gb + 1] + D1[6 + i] * xr[gb + 2];
  } else if (k < 288) {
    const int t = k - 128; const int i = t % 5; const int gb = 128 + t - i;
    const float* D2 = Dn + 10;
    acc = 0.f;
#pragma unroll
    for (int j = 0; j < 5; ++j) acc += D2[j * 5 + i] * xr[gb + j];
  } else {
    const int t = k - 288; const int i = t % 7; const int gb = 288 + t - i;
    const float* D3 = Dn + 35;
    acc = 0.f;
#pragma unroll
    for (int j = 0; j < 7; ++j) acc += D3[j * 7 + i] * xr[gb + j];
  }
  xo[idx] = f2bf(acc);
}

// ------------------------------- GEMM ---------------------------------------
// X [M,512] bf16 row-major; Wt [512,512] bf16 (Wt[c][k] = W[k][c]); Y bf16.
__global__ __launch_bounds__(256) void gemm_xw(const ushort_t* __restrict__ X,
                                               const ushort_t* __restrict__ Wt,
                                               ushort_t* __restrict__ Y) {
  __shared__ ushort_t lA[128 * 64];
  __shared__ ushort_t lB[128 * 64];
  const int tid = threadIdx.x;
  const int lane = tid & 63;
  const int w = tid >> 6;            // wave 0..3
  const int wr = w >> 1, wc = w & 1; // 2x2 wave grid, 64x64 each
  const size_t n0 = (size_t)blockIdx.x * 128;
  const int c0 = blockIdx.y * 128;

  f32x4 acc[4][4];
#pragma unroll
  for (int a = 0; a < 4; ++a)
#pragma unroll
    for (int b = 0; b < 4; ++b) acc[a][b] = (f32x4){0.f, 0.f, 0.f, 0.f};

  const int arow = lane >> 3;            // 0..7 (row within 1KB chunk)
  const int acolb = (lane & 7) * 16;     // byte within 128B row
  const char* Xg = (const char*)X;
  const char* Wg = (const char*)Wt;
  const int lr = lane & 15, lk = lane >> 4;

  for (int kt = 0; kt < 8; ++kt) {       // K = 512, BK = 64
#pragma unroll
    for (int i = 0; i < 4; ++i) {
      const int ch = w * 4 + i;          // 16 chunks of 1KB per 16KB tile
      gload_lds16(Xg + (n0 + (size_t)(ch * 8 + arow)) * 1024 + kt * 128 + acolb,
                  (char*)lA + ch * 1024);
      gload_lds16(Wg + (size_t)(c0 + ch * 8 + arow) * 1024 + kt * 128 + acolb,
                  (char*)lB + ch * 1024);
    }
    __syncthreads();
#pragma unroll
    for (int ks = 0; ks < 2; ++ks) {
      bf16x8 af[4], bf[4];
#pragma unroll
      for (int mr = 0; mr < 4; ++mr)
        af[mr] = *(const bf16x8*)&lA[(wr * 64 + mr * 16 + lr) * 64 + ks * 32 + lk * 8];
#pragma unroll
      for (int nc = 0; nc < 4; ++nc)
        bf[nc] = *(const bf16x8*)&lB[(wc * 64 + nc * 16 + lr) * 64 + ks * 32 + lk * 8];
#pragma unroll
      for (int mr = 0; mr < 4; ++mr)
#pragma unroll
        for (int nc = 0; nc < 4; ++nc)
          acc[mr][nc] = __builtin_amdgcn_mfma_f32_16x16x32_bf16(af[mr], bf[nc], acc[mr][nc], 0, 0, 0);
    }
    __syncthreads();
  }
  // epilogue: C/D layout col=lane&15, row=(lane>>4)*4+reg (m89-verified)
#pragma unroll
  for (int mr = 0; mr < 4; ++mr)
#pragma unroll
    for (int nc = 0; nc < 4; ++nc) {
      const int row = wr * 64 + mr * 16 + ((lane >> 4) << 2);
      const int col = c0 + wc * 64 + nc * 16 + (lane & 15);
#pragma unroll
      for (int j = 0; j < 4; ++j)
        Y[(n0 + row + j) * 512 + col] = f2bf(acc[mr][nc][j]);
    }
}

// ----------------------- forward rotate -> f32 out --------------------------
__global__ void rotate_fwd(const ushort_t* __restrict__ y, const float* __restrict__ Dm,
                           float* __restrict__ out, long long total) {
  long long idx = (long long)blockIdx.x * blockDim.x + threadIdx.x;
  if (idx >= total) return;
  const int k = (int)(idx & 511);
  const long long n = idx >> 9;
  const float* Dn = Dm + n * 84;
  const ushort_t* yr = y + (n << 9);
  float acc;
  if (k < 32) {
    acc = bf2f(yr[k]);
  } else if (k < 128) {
    const int t = k - 32; const int i = t % 3; const int gb = 32 + t - i;
    const float* D1 = Dn + 1;
    acc = D1[i * 3 + 0] * bf2f(yr[gb]) + D1[i * 3 + 1] * bf2f(yr[gb + 1]) + D1[i * 3 + 2] * bf2f(yr[gb + 2]);
  } else if (k < 288) {
    const int t = k - 128; const int i = t % 5; const int gb = 128 + t - i;
    const float* D2 = Dn + 10;
    acc = 0.f;
#pragma unroll
    for (int j = 0; j < 5; ++j) acc += D2[i * 5 + j] * bf2f(yr[gb + j]);
  } else {
    const int t = k - 288; const int i = t % 7; const int gb = 288 + t - i;
    const float* D3 = Dn + 35;
    acc = 0.f;
#pragma unroll
    for (int j = 0; j < 7; ++j) acc += D3[i * 7 + j] * bf2f(yr[gb + j]);
  }
  out[idx] = acc;
}

// ------------------------------- launch -------------------------------------
extern "C" void kernel_launch(void* const* d_in, const int* in_sizes, int n_in,
                              void* d_out, int out_size, void* d_ws, size_t ws_size,
                              hipStream_t stream) {
  const float* inp = (const float*)d_in[0];   // [N, 512] f32
  const float* vec = (const float*)d_in[1];   // [N, 3]   f32
  const float* W   = (const float*)d_in[2];   // [512, 512] f32
  float* out = (float*)d_out;                 // [N, 512] f32
  const int N = in_sizes[1] / 3;

  char* ws = (char*)d_ws;
  ushort_t* Wt = (ushort_t*)(ws + 0);                    // 512 KB
  float*    Dm = (float*)(ws + 524288);                  // N*84*4 = 44 MB
  ushort_t* Xb = (ushort_t*)(ws + 44564480ULL);          // N*512*2 = 134 MB
  ushort_t* Yb = (ushort_t*)(ws + 178782208ULL);         // N*512*2 = 134 MB

  const long long total = (long long)N * 512;

  convert_Wt<<<1024, 256, 0, stream>>>(W, Wt);
  compute_D<<<(N + 255) / 256, 256, 0, stream>>>(vec, Dm, N);
  rotate_inv<<<(unsigned)(total / 256), 256, 0, stream>>>(inp, Dm, Xb, total);
  dim3 g(N / 128, 4);
  gemm_xw<<<g, 256, 0, stream>>>(Xb, Wt, Yb);
  rotate_fwd<<<(unsigned)(total / 256), 256, 0, stream>>>(Yb, Dm, out, total);
}

// Round 4
// 797.359 us; speedup vs baseline: 1.3898x; 1.3898x over previous
//
#include <hip/hip_runtime.h>

// ---------------------------------------------------------------------------
// TensorProductWithSphericalHarmonicsLinear: out = R(v) * ((R(v)^T * x) @ W)
// R block-diagonal per irrep (32x0e+32x1o+32x2e+32x3o), Wigner D(alpha,beta,0).
// D = exp(alpha*X1) * exp(beta*X0) via compile-time spectral projectors.
// Round 4: row-per-wave LDS-staged rotate kernels (vectorized), BN=512 GEMM
// (X read once), coalesced compute_D. Math identical to the r3 PASS kernel.
// ---------------------------------------------------------------------------

typedef unsigned short ushort_t;
typedef unsigned int uint32;
typedef __attribute__((ext_vector_type(8))) short bf16x8;
typedef __attribute__((ext_vector_type(4))) float f32x4;
typedef __attribute__((ext_vector_type(4))) uint32 u32x4;

// ------------------------- compile-time fixed matrices ----------------------
struct FixTable { float v[495]; };  // l=1 @0 (27), l=2 @27 (125), l=3 @152 (343)

constexpr double csqrt(double x) {
  double g = x > 1.0 ? x : 1.0;
  for (int i = 0; i < 48; ++i) g = 0.5 * (g + x / g);
  return g;
}

constexpr FixTable make_fix() {
  FixTable F{};
  const double is2 = 1.0 / csqrt(2.0);
  for (int l = 1; l <= 3; ++l) {
    const int d = 2 * l + 1;
    const int base = (l == 1) ? 0 : (l == 2 ? 27 : 152);
    double Qre[7][7] = {}, Qim[7][7] = {};
    for (int m = -l; m < 0; ++m) {
      Qre[l + m][l - m] = is2;
      Qim[l + m][l + m] = -is2;
    }
    Qre[l][l] = 1.0;
    for (int m = 1; m <= l; ++m) {
      const double s = (m & 1) ? -1.0 : 1.0;
      Qre[l + m][l + m] = s * is2;
      Qim[l + m][l - m] = s * is2;
    }
    double X0c[7][7] = {};
    for (int r = 0; r + 1 < d; ++r) {
      const double mm = (double)(r - l);
      const double am = 0.5 * csqrt((double)(l * (l + 1)) - mm * (mm + 1.0));
      X0c[r][r + 1] = am;
      X0c[r + 1][r] = -am;
    }
    double Tre[7][7] = {}, Tim[7][7] = {};
    for (int i = 0; i < d; ++i)
      for (int j = 0; j < d; ++j) {
        double sre = 0.0, sim = 0.0;
        for (int r = 0; r < d; ++r) { sre += X0c[i][r] * Qre[r][j]; sim += X0c[i][r] * Qim[r][j]; }
        Tre[i][j] = sre; Tim[i][j] = sim;
      }
    double X0r[7][7] = {};
    for (int p = 0; p < d; ++p)
      for (int q = 0; q < d; ++q) {
        double s = 0.0;
        for (int r = 0; r < d; ++r) s += Qre[r][p] * Tre[r][q] + Qim[r][p] * Tim[r][q];
        X0r[p][q] = s;
      }
    double S[7][7] = {};
    for (int i = 0; i < d; ++i)
      for (int j = 0; j < d; ++j) {
        double s = 0.0;
        for (int r = 0; r < d; ++r) s += X0r[i][r] * X0r[r][j];
        S[i][j] = -s;
      }
    for (int m = 0; m <= l; ++m) {
      double P[7][7] = {};
      for (int i = 0; i < d; ++i) P[i][i] = 1.0;
      for (int k = 0; k <= l; ++k) {
        if (k == m) continue;
        double Pn[7][7] = {};
        const double den = (double)(m * m - k * k);
        for (int i = 0; i < d; ++i)
          for (int j = 0; j < d; ++j) {
            double s = 0.0;
            for (int r = 0; r < d; ++r) s += P[i][r] * S[r][j];
            Pn[i][j] = (s - (double)(k * k) * P[i][j]) / den;
          }
        for (int i = 0; i < d; ++i)
          for (int j = 0; j < d; ++j) P[i][j] = Pn[i][j];
      }
      for (int i = 0; i < d; ++i)
        for (int j = 0; j < d; ++j)
          F.v[base + m * d * d + i * d + j] = (float)P[i][j];
      if (m >= 1) {
        for (int i = 0; i < d; ++i)
          for (int j = 0; j < d; ++j) {
            double s = 0.0;
            for (int r = 0; r < d; ++r) s += X0r[i][r] * P[r][j];
            F.v[base + (l + 1) * d * d + (m - 1) * d * d + i * d + j] = (float)(s / (double)m);
          }
      }
    }
  }
  return F;
}

__constant__ FixTable c_fix = make_fix();

// ------------------------------- helpers -----------------------------------
__device__ __forceinline__ ushort_t f2bf(float f) {
  uint32 u = __builtin_bit_cast(uint32, f);
  uint32 r = (u + 0x7FFFu + ((u >> 16) & 1u)) >> 16;
  return (ushort_t)r;
}
__device__ __forceinline__ float bf2f(ushort_t b) {
  uint32 u = ((uint32)b) << 16;
  return __builtin_bit_cast(float, u);
}
__device__ __forceinline__ void gload_lds16(const void* g, void* l) {
  __builtin_amdgcn_global_load_lds((const __attribute__((address_space(1))) void*)g,
                                   (__attribute__((address_space(3))) void*)l, 16, 0, 0);
}

// --------------------------- W -> W^T (bf16) --------------------------------
__global__ void convert_Wt(const float* __restrict__ W, ushort_t* __restrict__ Wt) {
  int idx = blockIdx.x * 256 + threadIdx.x;  // 512*512 total
  int k = idx & 511, c = idx >> 9;
  Wt[c * 512 + k] = f2bf(W[k * 512 + c]);
}

// --------------------------- per-row Wigner D -------------------------------
template <int L>
__device__ __forceinline__ void makeD(const float* __restrict__ fixl,
                                      const float* ca, const float* sa,
                                      const float* cb, const float* sb,
                                      float* __restrict__ out) {
  constexpr int d = 2 * L + 1;
  float E[d * d];
#pragma unroll
  for (int i = 0; i < d * d; ++i) E[i] = fixl[i];
#pragma unroll
  for (int m = 1; m <= L; ++m) {
    const float* Cm = fixl + m * d * d;
    const float* Sm = fixl + (L + 1) * d * d + (m - 1) * d * d;
#pragma unroll
    for (int i = 0; i < d * d; ++i) E[i] += cb[m] * Cm[i] + sb[m] * Sm[i];
  }
#pragma unroll
  for (int m = 1; m <= L; ++m) {
#pragma unroll
    for (int j = 0; j < d; ++j) {
      float lo = E[(L - m) * d + j], hi = E[(L + m) * d + j];
      E[(L - m) * d + j] = ca[m] * lo + sa[m] * hi;
      E[(L + m) * d + j] = -sa[m] * lo + ca[m] * hi;
    }
  }
#pragma unroll
  for (int i = 0; i < d * d; ++i) out[i] = E[i];
}

// 128 threads: each computes one row's 84-float D into LDS, then coalesced write.
__global__ __launch_bounds__(128) void compute_D(const float* __restrict__ vec,
                                                 float* __restrict__ Dout, int N) {
  __shared__ __attribute__((aligned(16))) float ds[128 * 84];  // 43 KB
  const int tid = threadIdx.x;
  const int n = blockIdx.x * 128 + tid;
  float vx = vec[3 * n + 0], vy = vec[3 * n + 1], vz = vec[3 * n + 2];
  float r = sqrtf(vx * vx + vy * vy + vz * vz);
  float xx = fminf(fmaxf(vx / r, -1.f), 1.f);
  float yy = fminf(fmaxf(vy / r, -1.f), 1.f);
  float zz = fminf(fmaxf(vz / r, -1.f), 1.f);
  float beta = acosf(yy);
  float alpha = atan2f(xx, zz);
  float ca[4], sa[4], cb[4], sb[4];
#pragma unroll
  for (int m = 1; m <= 3; ++m) {
    ca[m] = cosf((float)m * alpha); sa[m] = sinf((float)m * alpha);
    cb[m] = cosf((float)m * beta);  sb[m] = sinf((float)m * beta);
  }
  float* Dn = ds + tid * 84;
  Dn[0] = 1.f;
  makeD<1>(c_fix.v + 0,   ca, sa, cb, sb, Dn + 1);
  makeD<2>(c_fix.v + 27,  ca, sa, cb, sb, Dn + 10);
  makeD<3>(c_fix.v + 152, ca, sa, cb, sb, Dn + 35);
  __syncthreads();
  float* dst = Dout + (size_t)blockIdx.x * (128 * 84);
  for (int i = tid; i < 128 * 84; i += 128) dst[i] = ds[i];
}

// ----------------------- inverse rotate -> bf16 x ---------------------------
// One wave per row; row + D staged in LDS; vectorized IO.
__global__ __launch_bounds__(256) void rotate_inv(const float* __restrict__ in,
                                                  const float* __restrict__ Dm,
                                                  ushort_t* __restrict__ xo, int N) {
  __shared__ __attribute__((aligned(16))) float rb[4][512];
  __shared__ __attribute__((aligned(16))) float db[4][84];
  const int w = threadIdx.x >> 6, lane = threadIdx.x & 63;
#pragma unroll 1
  for (int it = 0; it < 16; ++it) {
    const int n = blockIdx.x * 64 + it * 4 + w;
    const float4* src = (const float4*)(in + (size_t)n * 512);
    float4 a = src[lane * 2], b = src[lane * 2 + 1];
    *(float4*)&rb[w][lane * 8] = a;
    *(float4*)&rb[w][lane * 8 + 4] = b;
    if (lane < 21)
      *(float4*)&db[w][lane * 4] = *(const float4*)(Dm + (size_t)n * 84 + lane * 4);
    __syncthreads();
    const float* xr = rb[w];
    const float* Dn = db[w];
    float o[8];
#pragma unroll
    for (int u = 0; u < 8; ++u) {
      const int k = lane * 8 + u;
      float acc;
      if (k < 32) {
        acc = xr[k];
      } else if (k < 128) {
        const int t = k - 32; const int i = t % 3; const int gb = 32 + t - i;
        const float* D1 = Dn + 1;
        acc = D1[i] * xr[gb] + D1[3 + i] * xr[gb + 1] + D1[6 + i] * xr[gb + 2];
      } else if (k < 288) {
        const int t = k - 128; const int i = t % 5; const int gb = 128 + t - i;
        const float* D2 = Dn + 10;
        acc = 0.f;
#pragma unroll
        for (int j = 0; j < 5; ++j) acc += D2[j * 5 + i] * xr[gb + j];
      } else {
        const int t = k - 288; const int i = t % 7; const int gb = 288 + t - i;
        const float* D3 = Dn + 35;
        acc = 0.f;
#pragma unroll
        for (int j = 0; j < 7; ++j) acc += D3[j * 7 + i] * xr[gb + j];
      }
      o[u] = acc;
    }
    u32x4 pk;
#pragma unroll
    for (int u = 0; u < 4; ++u)
      pk[u] = (uint32)f2bf(o[2 * u]) | ((uint32)f2bf(o[2 * u + 1]) << 16);
    *(u32x4*)(xo + (size_t)n * 512 + lane * 8) = pk;
    __syncthreads();
  }
}

// ------------------------------- GEMM ---------------------------------------
// X [M,512] bf16 row-major; Wt [512,512] bf16 (Wt[c][k] = W[k][c]); Y bf16.
// BM=128, BN=512 (full width, X read once), BK=64; 8 waves (2 row x 4 col).
__global__ __launch_bounds__(512) void gemm_xw(const ushort_t* __restrict__ X,
                                               const ushort_t* __restrict__ Wt,
                                               ushort_t* __restrict__ Y) {
  __shared__ ushort_t lA[128 * 64];   // 16 KB
  __shared__ ushort_t lB[512 * 64];   // 64 KB
  const int tid = threadIdx.x;
  const int lane = tid & 63;
  const int w = tid >> 6;             // wave 0..7
  const int wr = w >> 2, wc = w & 3;  // 2x4 wave grid: 64 rows x 128 cols each
  const size_t n0 = (size_t)blockIdx.x * 128;

  f32x4 acc[4][8];
#pragma unroll
  for (int a = 0; a < 4; ++a)
#pragma unroll
    for (int b = 0; b < 8; ++b) acc[a][b] = (f32x4){0.f, 0.f, 0.f, 0.f};

  const char* Xg = (const char*)X;
  const char* Wg = (const char*)Wt;
  const int lr = lane & 15, lk = lane >> 4;

  for (int kt = 0; kt < 8; ++kt) {    // K = 512, BK = 64
    // stage A: 1024 x 16B chunks, 2 per thread
#pragma unroll
    for (int i = 0; i < 2; ++i) {
      const int o = (i * 512 + tid) * 16;
      const int row = o >> 7, colb = o & 127;
      gload_lds16(Xg + (n0 + (size_t)row) * 1024 + kt * 128 + colb, (char*)lA + o);
    }
    // stage B: 4096 x 16B chunks, 8 per thread
#pragma unroll
    for (int i = 0; i < 8; ++i) {
      const int o = (i * 512 + tid) * 16;
      const int row = o >> 7, colb = o & 127;
      gload_lds16(Wg + (size_t)row * 1024 + kt * 128 + colb, (char*)lB + o);
    }
    __syncthreads();
#pragma unroll
    for (int ks = 0; ks < 2; ++ks) {
      bf16x8 af[4], bfr[8];
#pragma unroll
      for (int m = 0; m < 4; ++m)
        af[m] = *(const bf16x8*)&lA[(wr * 64 + m * 16 + lr) * 64 + ks * 32 + lk * 8];
#pragma unroll
      for (int nn = 0; nn < 8; ++nn)
        bfr[nn] = *(const bf16x8*)&lB[(wc * 128 + nn * 16 + lr) * 64 + ks * 32 + lk * 8];
#pragma unroll
      for (int m = 0; m < 4; ++m)
#pragma unroll
        for (int nn = 0; nn < 8; ++nn)
          acc[m][nn] = __builtin_amdgcn_mfma_f32_16x16x32_bf16(af[m], bfr[nn], acc[m][nn], 0, 0, 0);
    }
    __syncthreads();
  }
  // epilogue: C/D layout col=lane&15, row=(lane>>4)*4+reg (m89-verified)
#pragma unroll
  for (int m = 0; m < 4; ++m)
#pragma unroll
    for (int nn = 0; nn < 8; ++nn) {
      const int row = wr * 64 + m * 16 + ((lane >> 4) << 2);
      const int col = wc * 128 + nn * 16 + lr;
#pragma unroll
      for (int j = 0; j < 4; ++j)
        Y[(n0 + row + j) * 512 + col] = f2bf(acc[m][nn][j]);
    }
}

// ----------------------- forward rotate -> f32 out --------------------------
__global__ __launch_bounds__(256) void rotate_fwd(const ushort_t* __restrict__ y,
                                                  const float* __restrict__ Dm,
                                                  float* __restrict__ out, int N) {
  __shared__ __attribute__((aligned(16))) float rb[4][512];
  __shared__ __attribute__((aligned(16))) float db[4][84];
  const int w = threadIdx.x >> 6, lane = threadIdx.x & 63;
#pragma unroll 1
  for (int it = 0; it < 16; ++it) {
    const int n = blockIdx.x * 64 + it * 4 + w;
    const bf16x8 v = *(const bf16x8*)(y + (size_t)n * 512 + lane * 8);
#pragma unroll
    for (int u = 0; u < 8; ++u) rb[w][lane * 8 + u] = bf2f((ushort_t)v[u]);
    if (lane < 21)
      *(float4*)&db[w][lane * 4] = *(const float4*)(Dm + (size_t)n * 84 + lane * 4);
    __syncthreads();
    const float* yr = rb[w];
    const float* Dn = db[w];
    float o[8];
#pragma unroll
    for (int u = 0; u < 8; ++u) {
      const int k = lane * 8 + u;
      float acc;
      if (k < 32) {
        acc = yr[k];
      } else if (k < 128) {
        const int t = k - 32; const int i = t % 3; const int gb = 32 + t - i;
        const float* D1 = Dn + 1;
        acc = D1[i * 3 + 0] * yr[gb] + D1[i * 3 + 1] * yr[gb + 1] + D1[i * 3 + 2] * yr[gb + 2];
      } else if (k < 288) {
        const int t = k - 128; const int i = t % 5; const int gb = 128 + t - i;
        const float* D2 = Dn + 10;
        acc = 0.f;
#pragma unroll
        for (int j = 0; j < 5; ++j) acc += D2[i * 5 + j] * yr[gb + j];
      } else {
        const int t = k - 288; const int i = t % 7; const int gb = 288 + t - i;
        const float* D3 = Dn + 35;
        acc = 0.f;
#pragma unroll
        for (int j = 0; j < 7; ++j) acc += D3[i * 7 + j] * yr[gb + j];
      }
      o[u] = acc;
    }
    float* dst = out + (size_t)n * 512 + lane * 8;
    *(float4*)dst = (float4){o[0], o[1], o[2], o[3]};
    *(float4*)(dst + 4) = (float4){o[4], o[5], o[6], o[7]};
    __syncthreads();
  }
}

// ------------------------------- launch -------------------------------------
extern "C" void kernel_launch(void* const* d_in, const int* in_sizes, int n_in,
                              void* d_out, int out_size, void* d_ws, size_t ws_size,
                              hipStream_t stream) {
  const float* inp = (const float*)d_in[0];   // [N, 512] f32
  const float* vec = (const float*)d_in[1];   // [N, 3]   f32
  const float* W   = (const float*)d_in[2];   // [512, 512] f32
  float* out = (float*)d_out;                 // [N, 512] f32
  const int N = in_sizes[1] / 3;              // 131072

  char* ws = (char*)d_ws;
  ushort_t* Wt = (ushort_t*)(ws + 0);                    // 512 KB
  float*    Dm = (float*)(ws + 524288);                  // N*84*4 = 44 MB
  ushort_t* Xb = (ushort_t*)(ws + 44564480ULL);          // N*512*2 = 134 MB
  ushort_t* Yb = (ushort_t*)(ws + 178782208ULL);         // N*512*2 = 134 MB

  convert_Wt<<<1024, 256, 0, stream>>>(W, Wt);
  compute_D<<<N / 128, 128, 0, stream>>>(vec, Dm, N);
  rotate_inv<<<N / 64, 256, 0, stream>>>(inp, Dm, Xb, N);
  gemm_xw<<<N / 128, 512, 0, stream>>>(Xb, Wt, Yb);
  rotate_fwd<<<N / 64, 256, 0, stream>>>(Yb, Dm, out, N);
}